// Round 8
// baseline (173.268 us; speedup 1.0000x reference)
//
#include <hip/hip_runtime.h>

#define Bn 256
#define Sn 1024
#define Tn 64
#define NCH 16
#define BURN 64
#define SLAB 4
#define RAWD 5              // raw ring depth (slabs in flight: r+2..r+5)
#define RAWSTR 260          // raw f32 per-mm stride (256 + 4 pad)
#define CROW 72             // conv/alpha bf16 row stride in shorts
#define MROW 129
#define LN2 0.69314718055994531f
#define L7LN2 4.8520302639196169f   // 7*ln2 (lambda = 2^-7 folded into exp)

typedef __attribute__((ext_vector_type(8))) short short8;
typedef __attribute__((ext_vector_type(4))) float f32x4;

// raw s_barrier + hand-placed waits: NEVER vmcnt(0) in the hot loop.
// vmcnt retires in issue order (m135): outstanding<=N ==> all older landed.
#define BAR_W0_V48() asm volatile("s_waitcnt vmcnt(48) lgkmcnt(0)\n\ts_barrier" ::: "memory")
#define BAR_W0_V32() asm volatile("s_waitcnt vmcnt(32) lgkmcnt(0)\n\ts_barrier" ::: "memory")
#define BAR_W0_V16() asm volatile("s_waitcnt vmcnt(16) lgkmcnt(0)\n\ts_barrier" ::: "memory")
#define BAR_FULL()   asm volatile("s_waitcnt vmcnt(0) lgkmcnt(0)\n\ts_barrier" ::: "memory")

__device__ __forceinline__ unsigned short f2bf_rne(float f) {
  unsigned u = __float_as_uint(f);
  u = (u + 0x7fffu + ((u >> 16) & 1u)) >> 16;
  return (unsigned short)u;
}
__device__ __forceinline__ unsigned pk2(float hi, float lo) {
  return __builtin_amdgcn_perm(__float_as_uint(hi), __float_as_uint(lo), 0x07060302);
}
__device__ __forceinline__ unsigned pke(float a, float b) {  // exp+pack 2 bf16
  return (unsigned)f2bf_rne(__expf(a - L7LN2)) |
         ((unsigned)f2bf_rne(__expf(b - L7LN2)) << 16);
}
__device__ __forceinline__ void gl_lds16(const void* src, void* dst) {
  __builtin_amdgcn_global_load_lds(
      (const __attribute__((address_space(1))) void*)src,
      (__attribute__((address_space(3))) void*)dst, 16, 0, 0);
}
__device__ __forceinline__ void gl_lds4(const void* src, void* dst) {
  __builtin_amdgcn_global_load_lds(
      (const __attribute__((address_space(1))) void*)src,
      (__attribute__((address_space(3))) void*)dst, 4, 0, 0);
}

// 256 blocks = 16 batch-groups x 16 chunks; 128 threads:
//   wave0: issues raw-em global_load_lds (4 slabs ahead) + MFMA vector scan
//   wave1: mask staging, gold partials, raw->exp'd-bf16 slab conversion
// Fused finale: last block (atomic count) reduces everything to out[0].
__global__ __launch_bounds__(128, 1) void crf_scan(
    const float* __restrict__ em, const int* __restrict__ tags,
    const int* __restrict__ mask, const float* __restrict__ trans,
    const float* __restrict__ startt, const float* __restrict__ endt,
    float* __restrict__ wsL, float* __restrict__ wsGold,
    int* __restrict__ wsM, float* __restrict__ wsSE, float* __restrict__ wsA,
    int* __restrict__ cnt, float* __restrict__ out) {
  const int g = blockIdx.x & 15;
  const int c = blockIdx.x >> 4;
  const int Wc = (c == 0) ? 0 : BURN;
  const int Lc = (c == NCH - 1) ? 63 : 64;
  const int TOT = Wc + Lc;
  const int NSLAB = (TOT + SLAB - 1) / SLAB;   // >= 16 always
  const int t0 = 64 * c + 1;
  const int tstart = t0 - Wc;
  const int tid = threadIdx.x;
  const int wid = tid >> 6;
  const int lane = tid & 63;
  const int m = lane & 15;
  const int q = lane >> 4;

  __shared__ __align__(16) float rawS[RAWD][16 * RAWSTR];   // 83 KB raw em ring
  __shared__ __align__(16) short convS[2][SLAB * 16 * CROW];// 18.4 KB exp'd bf16
  __shared__ __align__(16) short alpha[16 * CROW];          // 2.3 KB state rows
  __shared__ int maskL[16 * MROW];                          // 8.3 KB
  __shared__ int lastF;
  __shared__ float eend[64];
  __shared__ float rsum[2];

  short8 a00, a01, a10, a11, a20, a21, a30, a31;
  uint2 st0, st1, st2, st3;
  float Slog = 0.f;
  int K = 0, NL = 0;
  const f32x4 zero4 = {0.f, 0.f, 0.f, 0.f};

  auto issue_slab = [&](int s) {
    if (s >= NSLAB) return;
    float* dstb = rawS[s % RAWD];
    const int rem = TOT - 4 * s;
    if (rem >= SLAB) {   // full slabs always have t <= 1023: in-bounds
      for (int mm = 0; mm < 16; ++mm)
        gl_lds16(em + ((size_t)(16 * g + mm) * Sn + tstart + 4 * s) * 64 + lane * 4,
                 dstb + mm * RAWSTR);
    } else {             // final partial slab: per-step 4B loads, t <= 1023
      for (int mm = 0; mm < 16; ++mm)
        for (int u = 0; u < rem; ++u)
          gl_lds4(em + ((size_t)(16 * g + mm) * Sn + tstart + 4 * s + u) * 64 + lane,
                  dstb + mm * RAWSTR + u * 64);
    }
  };
  auto convert_slab = [&](int s) {
    if (s >= NSLAB) return;
    const int mm = lane & 15, seg = lane >> 4;
    const float* rp = rawS[s % RAWD] + mm * RAWSTR + seg * 16;
    short* cb = convS[s & 1];
    const int vu = min(SLAB, TOT - 4 * s);
    for (int u = 0; u < vu; ++u) {
      float4 v0 = *(const float4*)(rp + u * 64 + 0);
      float4 v1 = *(const float4*)(rp + u * 64 + 4);
      float4 v2 = *(const float4*)(rp + u * 64 + 8);
      float4 v3 = *(const float4*)(rp + u * 64 + 12);
      uint4 w0, w1;
      w0.x = pke(v0.x, v0.y); w0.y = pke(v0.z, v0.w);
      w0.z = pke(v1.x, v1.y); w0.w = pke(v1.z, v1.w);
      w1.x = pke(v2.x, v2.y); w1.y = pke(v2.z, v2.w);
      w1.z = pke(v3.x, v3.y); w1.w = pke(v3.z, v3.w);
      short* cw = cb + (u * 16 + mm) * CROW + seg * 16;
      *(uint4*)(cw) = w0;
      *(uint4*)(cw + 8) = w1;
    }
  };

  // ================= phase A =================
  if (wid == 0) {
    issue_slab(0);
    // A[j][k] = exp(trans[k][j]), j = 16*tm+m, k = kc*32+q*8+jj (R5-verified)
#define LOADA(tm, kc, dst) { \
    _Pragma("unroll") for (int jj = 0; jj < 8; ++jj) { \
      int kk = kc * 32 + q * 8 + jj; \
      dst[jj] = (short)f2bf_rne(__expf(trans[kk * Tn + 16 * tm + m])); \
    } }
    LOADA(0, 0, a00) LOADA(0, 1, a01) LOADA(1, 0, a10) LOADA(1, 1, a11)
    LOADA(2, 0, a20) LOADA(2, 1, a21) LOADA(3, 0, a30) LOADA(3, 1, a31)
#undef LOADA
    if (c == 0) {  // exact alpha_0 = exp(startt + em[:,0,:])
#define INIT0(tm, ss) { \
      float4 sv = *(const float4*)(startt + 16 * tm + 4 * q); \
      float4 ev = *(const float4*)(em + (size_t)(16 * g + m) * Sn * Tn + 16 * tm + 4 * q); \
      ss.x = (unsigned)f2bf_rne(__expf(sv.x + ev.x)) | \
             ((unsigned)f2bf_rne(__expf(sv.y + ev.y)) << 16); \
      ss.y = (unsigned)f2bf_rne(__expf(sv.z + ev.z)) | \
             ((unsigned)f2bf_rne(__expf(sv.w + ev.w)) << 16); }
      INIT0(0, st0) INIT0(1, st1) INIT0(2, st2) INIT0(3, st3)
#undef INIT0
    } else {
      st0.x = 0x3F803F80u; st0.y = 0x3F803F80u; st1 = st0; st2 = st0; st3 = st0;
    }
  } else {
    // ---- mask staging (async gl_lds) ----
    for (int mm = 0; mm < 16; ++mm) {
      gl_lds4(mask + (size_t)(16 * g + mm) * Sn + tstart + lane,
              (void*)(maskL + mm * MROW));
      bool special = (c == NCH - 1) && (g == 15) && (mm == 15);  // avoid OOB t=1024
      if (!special)
        gl_lds4(mask + (size_t)(16 * g + mm) * Sn + tstart + 64 + lane,
                (void*)(maskL + mm * MROW + 64));
    }
    // ---- gold partials, fully unrolled: 2 serialized latency levels ----
    {
      const int bm = 16 * g + m;
      const int* tg = tags + (size_t)bm * Sn;
      const int* mkb = mask + (size_t)bm * Sn;
      const float* emb = em + (size_t)bm * Sn * Tn;
      float acc = 0.f;
      int cntg = 0;
      #pragma unroll 16
      for (int i = 0; i < 16; ++i) {
        int t = t0 + q + 4 * i;
        bool ok = t < t0 + Lc;
        int ts = ok ? t : t0;
        int mv = mkb[ts];
        int tp = tg[ts - 1], tc = tg[ts];
        float w = trans[tp * Tn + tc] + emb[(size_t)ts * Tn + tc];
        acc += (ok && mv) ? w : 0.f;
        cntg += ok ? mv : 0;
      }
      acc += __shfl_xor(acc, 16); acc += __shfl_xor(acc, 32);
      cntg += __shfl_xor(cntg, 16); cntg += __shfl_xor(cntg, 32);
      if (q == 0) { wsGold[c * 256 + bm] = acc; wsM[c * 256 + bm] = cntg; }
    }
    if (c == NCH - 1 && g == 15) {  // repair skipped row, guarded plain loads
      int t = tstart + 64 + lane;
      if (t < Sn) maskL[15 * MROW + 64 + lane] = mask[(size_t)255 * Sn + t];
    }
  }
  BAR_FULL();   // raw slab0 + maskL ready (one full drain: prologue only)

  // ================= phase P: prime 4-deep pipeline =================
  if (wid == 0) {
    issue_slab(1); issue_slab(2); issue_slab(3); issue_slab(4);
    BAR_W0_V48();  // slab1 landed; slabs 2,3,4 stay in flight across barrier
  } else {
    convert_slab(0);
    BAR_FULL();
  }

  // ================= rounds =================
#define UNP(ss, x0, x1, x2, x3) \
  x0 = __uint_as_float(ss.x << 16); x1 = __uint_as_float(ss.x & 0xffff0000u); \
  x2 = __uint_as_float(ss.y << 16); x3 = __uint_as_float(ss.y & 0xffff0000u);

  for (int r = 0; r < NSLAB; ++r) {
    if (wid == 0) {
      issue_slab(r + 5);  // 4 rounds ahead
      const short* cbase = convS[r & 1];
      short* arow = alpha + m * CROW;
      #pragma unroll
      for (int u = 0; u < SLAB; ++u) {
        const int tt = 4 * r + u;
        if (tt < TOT) {
          if (((r & 1) == 0) && u == 0) {  // renorm every 8 steps (exact pow2)
            float x00, x01, x02, x03, x10, x11, x12, x13;
            float x20, x21, x22, x23, x30, x31, x32, x33;
            UNP(st0, x00, x01, x02, x03) UNP(st1, x10, x11, x12, x13)
            UNP(st2, x20, x21, x22, x23) UNP(st3, x30, x31, x32, x33)
            float sm = (((x00 + x01) + (x02 + x03)) + ((x10 + x11) + (x12 + x13)))
                     + (((x20 + x21) + (x22 + x23)) + ((x30 + x31) + (x32 + x33)));
            sm += __shfl_xor(sm, 16); sm += __shfl_xor(sm, 32);
            if (c != 0 && tt == BURN) { Slog = __logf(sm); K = 0; NL = 0; }
            int k = 127 - (int)((__float_as_uint(sm) >> 23) & 255u);
            float fk = __uint_as_float((unsigned)(127 + k) << 23);
            x00 *= fk; x01 *= fk; x02 *= fk; x03 *= fk;
            x10 *= fk; x11 *= fk; x12 *= fk; x13 *= fk;
            x20 *= fk; x21 *= fk; x22 *= fk; x23 *= fk;
            x30 *= fk; x31 *= fk; x32 *= fk; x33 *= fk;
            st0.x = pk2(x01, x00); st0.y = pk2(x03, x02);
            st1.x = pk2(x11, x10); st1.y = pk2(x13, x12);
            st2.x = pk2(x21, x20); st2.y = pk2(x23, x22);
            st3.x = pk2(x31, x30); st3.y = pk2(x33, x32);
            K += k;
          }
          const short* ep = cbase + (u * 16 + m) * CROW;
          uint2 eu0 = *(const uint2*)(ep + 0 + 4 * q);
          uint2 eu1 = *(const uint2*)(ep + 16 + 4 * q);
          uint2 eu2 = *(const uint2*)(ep + 32 + 4 * q);
          uint2 eu3 = *(const uint2*)(ep + 48 + 4 * q);
          int mv = maskL[m * MROW + tt];
          *(uint2*)(arow + 4 * q) = st0;
          *(uint2*)(arow + 16 + 4 * q) = st1;
          *(uint2*)(arow + 32 + 4 * q) = st2;
          *(uint2*)(arow + 48 + 4 * q) = st3;
          short8 b0 = *(const short8*)(arow + q * 8);
          short8 b1 = *(const short8*)(arow + 32 + q * 8);
          f32x4 d0 = __builtin_amdgcn_mfma_f32_16x16x32_bf16(a00, b0, zero4, 0, 0, 0);
          f32x4 d1 = __builtin_amdgcn_mfma_f32_16x16x32_bf16(a10, b0, zero4, 0, 0, 0);
          f32x4 d2 = __builtin_amdgcn_mfma_f32_16x16x32_bf16(a20, b0, zero4, 0, 0, 0);
          f32x4 d3 = __builtin_amdgcn_mfma_f32_16x16x32_bf16(a30, b0, zero4, 0, 0, 0);
          d0 = __builtin_amdgcn_mfma_f32_16x16x32_bf16(a01, b1, d0, 0, 0, 0);
          d1 = __builtin_amdgcn_mfma_f32_16x16x32_bf16(a11, b1, d1, 0, 0, 0);
          d2 = __builtin_amdgcn_mfma_f32_16x16x32_bf16(a21, b1, d2, 0, 0, 0);
          d3 = __builtin_amdgcn_mfma_f32_16x16x32_bf16(a31, b1, d3, 0, 0, 0);
          const bool live = (mv != 0);
#define EPI(dd, eu, ss) { \
          float e0 = __uint_as_float(eu.x << 16); \
          float e1 = __uint_as_float(eu.x & 0xffff0000u); \
          float e2 = __uint_as_float(eu.y << 16); \
          float e3 = __uint_as_float(eu.y & 0xffff0000u); \
          unsigned nx = pk2(dd[1] * e1, dd[0] * e0); \
          unsigned ny = pk2(dd[3] * e3, dd[2] * e2); \
          ss.x = live ? nx : ss.x; \
          ss.y = live ? ny : ss.y; }
          EPI(d0, eu0, st0) EPI(d1, eu1, st1) EPI(d2, eu2, st2) EPI(d3, eu3, st3)
#undef EPI
          NL += (live && tt >= Wc) ? 1 : 0;
        }
      }
      // staged waits: ensure slab r+2 landed; keep newest slabs in flight.
      if (r + 5 < NSLAB)      { BAR_W0_V48(); }
      else if (r + 4 < NSLAB) { BAR_W0_V32(); }
      else if (r + 3 < NSLAB) { BAR_W0_V16(); }
      else                    { BAR_FULL(); }
    } else {
      convert_slab(r + 1);
      BAR_FULL();   // wave1: vmcnt trivially 0; lgkmcnt drains convS writes
    }
  }

  // ================= per-chunk outputs =================
  if (wid == 0) {
    float x00, x01, x02, x03, x10, x11, x12, x13;
    float x20, x21, x22, x23, x30, x31, x32, x33;
    UNP(st0, x00, x01, x02, x03) UNP(st1, x10, x11, x12, x13)
    UNP(st2, x20, x21, x22, x23) UNP(st3, x30, x31, x32, x33)
    float sm = (((x00 + x01) + (x02 + x03)) + ((x10 + x11) + (x12 + x13)))
             + (((x20 + x21) + (x22 + x23)) + ((x30 + x31) + (x32 + x33)));
    sm += __shfl_xor(sm, 16); sm += __shfl_xor(sm, 32);
    const int bm = 16 * g + m;
    float L = __logf(sm) - Slog + LN2 * (float)(7 * NL - K);
    if (q == 0) wsL[c * 256 + bm] = L;
    if (c == NCH - 1) {
      if (q == 0) wsSE[bm] = __logf(sm);
      wsA[(0 + 4 * q + 0) * 256 + bm] = x00;  wsA[(0 + 4 * q + 1) * 256 + bm] = x01;
      wsA[(0 + 4 * q + 2) * 256 + bm] = x02;  wsA[(0 + 4 * q + 3) * 256 + bm] = x03;
      wsA[(16 + 4 * q + 0) * 256 + bm] = x10; wsA[(16 + 4 * q + 1) * 256 + bm] = x11;
      wsA[(16 + 4 * q + 2) * 256 + bm] = x12; wsA[(16 + 4 * q + 3) * 256 + bm] = x13;
      wsA[(32 + 4 * q + 0) * 256 + bm] = x20; wsA[(32 + 4 * q + 1) * 256 + bm] = x21;
      wsA[(32 + 4 * q + 2) * 256 + bm] = x22; wsA[(32 + 4 * q + 3) * 256 + bm] = x23;
      wsA[(48 + 4 * q + 0) * 256 + bm] = x30; wsA[(48 + 4 * q + 1) * 256 + bm] = x31;
      wsA[(48 + 4 * q + 2) * 256 + bm] = x32; wsA[(48 + 4 * q + 3) * 256 + bm] = x33;
    }
  }
#undef UNP

  // ================= fused finale (last block) =================
  __threadfence();
  __syncthreads();
  if (tid == 0) lastF = (atomicAdd(cnt, 1) == 255) ? 1 : 0;
  __syncthreads();
  if (lastF) {
    __threadfence();
    if (tid < 64) eend[tid] = __expf(endt[tid]);
    __syncthreads();
    float vsum = 0.f;
    for (int bb = tid; bb < Bn; bb += 128) {
      float sumL = 0.f, gold = 0.f;
      int msum = 0;
      #pragma unroll
      for (int cc = 0; cc < NCH; ++cc) {
        sumL += wsL[cc * 256 + bb];
        gold += wsGold[cc * 256 + bb];
        msum += wsM[cc * 256 + bb];
      }
      msum += mask[(size_t)bb * Sn];  // t = 0
      float se = 0.f;
      #pragma unroll 8
      for (int jj = 0; jj < Tn; ++jj) se += wsA[jj * 256 + bb] * eend[jj];
      float logZ = sumL + __logf(se) - wsSE[bb];
      int tg0 = tags[(size_t)bb * Sn];
      int lastTag = tags[(size_t)bb * Sn + (msum - 1)];
      gold += startt[tg0] + em[(size_t)bb * Sn * Tn + tg0] + endt[lastTag];
      vsum += logZ - gold;
    }
    #pragma unroll
    for (int o = 32; o > 0; o >>= 1) vsum += __shfl_xor(vsum, o, 64);
    if (lane == 0) rsum[wid] = vsum;
    __syncthreads();
    if (tid == 0) out[0] = (rsum[0] + rsum[1]) * (1.0f / Bn);
  }
}

extern "C" void kernel_launch(void* const* d_in, const int* in_sizes, int n_in,
                              void* d_out, int out_size, void* d_ws, size_t ws_size,
                              hipStream_t stream) {
  const float* em     = (const float*)d_in[0];
  const int*   tags   = (const int*)d_in[1];
  const int*   mask   = (const int*)d_in[2];
  const float* trans  = (const float*)d_in[3];
  const float* startt = (const float*)d_in[4];
  const float* endt   = (const float*)d_in[5];
  float* out = (float*)d_out;

  float* wsL    = (float*)d_ws;               // [16*256]
  float* wsGold = wsL + NCH * 256;            // [16*256]
  int*   wsM    = (int*)(wsGold + NCH * 256); // [16*256]
  float* wsSE   = (float*)(wsM + NCH * 256);  // [256]
  float* wsA    = wsSE + 256;                 // [64*256]
  int*   cnt    = (int*)(wsA + 64 * 256);     // [1] last-block counter

  hipMemsetAsync(cnt, 0, sizeof(int), stream);
  crf_scan<<<256, 128, 0, stream>>>(em, tags, mask, trans, startt, endt,
                                    wsL, wsGold, wsM, wsSE, wsA, cnt, out);
}